// Round 19
// baseline (192.961 us; speedup 1.0000x reference)
//
#include <hip/hip_runtime.h>

#define IN_F 256
#define HID1 128
#define HID2 64
#define NBLK 256      // edge-partition blocks
#define RB_LOG 8
#define RB 256        // nodes per bucket -> nbk = 391 for N=100000

typedef __bf16 bf16x8 __attribute__((ext_vector_type(8)));
typedef float f32x4 __attribute__((ext_vector_type(4)));
typedef unsigned short ushort8 __attribute__((ext_vector_type(8)));
typedef unsigned long long u64;

__device__ inline unsigned short f2bf(float f) {
    unsigned int u = __float_as_uint(f);
    u += 0x7fffu + ((u >> 16) & 1u);
    return (unsigned short)(u >> 16);
}
__device__ inline float bf2f(unsigned short u) {
    return __uint_as_float(((unsigned int)u) << 16);
}

// ---------------- index-format detection (sampled: first nOdd odd words) ----------------
__global__ void detect_kernel(const int* __restrict__ e, long long nOdd, int* flag) {
    long long stride = (long long)gridDim.x * blockDim.x;
    for (long long i = (long long)blockIdx.x * blockDim.x + threadIdx.x; i < nOdd; i += stride) {
        if (e[2 * i + 1] != 0) { *flag = 1; return; }
    }
}

__device__ inline int edge_src(const void* e, const int is32, long long i, int E) {
    return is32 ? ((const int*)e)[i] : (int)((const long long*)e)[i];
}
__device__ inline int edge_dst(const void* e, const int is32, long long i, int E) {
    return is32 ? ((const int*)e)[E + i] : (int)((const long long*)e)[E + i];
}

// ---------------- P1: per-block bucket histograms (LDS, no global atomics) ----------------
__global__ __launch_bounds__(256) void p1_count_kernel(const void* __restrict__ e,
                                                       const int* __restrict__ flag,
                                                       int* __restrict__ bhist,
                                                       int N, int E, int nbk, int chunk) {
    __shared__ int hist[512];
    const int is32 = *flag;
    const int blk = blockIdx.x;
    const int t = threadIdx.x;
    for (int j = t; j < nbk; j += 256) hist[j] = 0;
    __syncthreads();
    long long lo = (long long)blk * chunk;
    long long hi = lo + chunk; if (hi > E) hi = E;
    for (long long i = lo + t; i < hi; i += 256) {
        int s = edge_src(e, is32, i, E);
        int d = edge_dst(e, is32, i, E);
        if ((unsigned)s < (unsigned)N && (unsigned)d < (unsigned)N)
            atomicAdd(&hist[d >> RB_LOG], 1);
    }
    __syncthreads();
    for (int j = t; j < nbk; j += 256) bhist[j * NBLK + blk] = hist[j];   // bucket-major
}

// ---------------- P2a: exclusive scan of each bucket row (256 entries) ----------------
__global__ __launch_bounds__(256) void p2a_kernel(int* __restrict__ bhist, int* __restrict__ tot) {
    __shared__ int wsums[4], wpre[4];
    const int b = blockIdx.x;
    const int t = threadIdx.x;
    int v = bhist[b * NBLK + t];
    const int lane = t & 63;
    int x = v;
#pragma unroll
    for (int off = 1; off < 64; off <<= 1) {
        int y = __shfl_up(x, off, 64);
        if (lane >= off) x += y;
    }
    if (lane == 63) wsums[t >> 6] = x;
    __syncthreads();
    if (t == 0) { int r = 0; for (int w = 0; w < 4; w++) { wpre[w] = r; r += wsums[w]; } }
    __syncthreads();
    int excl = wpre[t >> 6] + x - v;
    bhist[b * NBLK + t] = excl;
    if (t == 255) tot[b] = excl + v;
}

// ---------------- P2b: scan bucket totals -> bstart (512-thread shfl scan) ----------------
__global__ __launch_bounds__(512) void p2b_kernel(const int* __restrict__ tot,
                                                  int* __restrict__ bstart,
                                                  int* __restrict__ rowptr, int nbk, int N) {
    __shared__ int wsums[8], wpre[8];
    const int t = threadIdx.x;
    int v = (t < nbk) ? tot[t] : 0;
    const int lane = t & 63;
    int x = v;
#pragma unroll
    for (int off = 1; off < 64; off <<= 1) {
        int y = __shfl_up(x, off, 64);
        if (lane >= off) x += y;
    }
    if (lane == 63) wsums[t >> 6] = x;
    __syncthreads();
    if (t == 0) { int r = 0; for (int w = 0; w < 8; w++) { wpre[w] = r; r += wsums[w]; } }
    __syncthreads();
    int excl = wpre[t >> 6] + x - v;
    if (t < nbk) bstart[t] = excl;
    if (t == 511) {
        int total = wpre[7] + wsums[7];
        bstart[nbk] = total;
        rowptr[N] = total;
    }
}

// ---------------- P3: scatter edges into bucket-major ebuf (LDS cursors) ----------------
__global__ __launch_bounds__(256) void p3_scatter_kernel(const void* __restrict__ e,
                                                         const int* __restrict__ flag,
                                                         const int* __restrict__ bhist,
                                                         const int* __restrict__ bstart,
                                                         u64* __restrict__ ebuf,
                                                         int N, int E, int nbk, int chunk) {
    __shared__ int cur[512];
    const int is32 = *flag;
    const int blk = blockIdx.x;
    const int t = threadIdx.x;
    for (int j = t; j < nbk; j += 256) cur[j] = bhist[j * NBLK + blk] + bstart[j];
    __syncthreads();
    long long lo = (long long)blk * chunk;
    long long hi = lo + chunk; if (hi > E) hi = E;
    for (long long i = lo + t; i < hi; i += 256) {
        int s = edge_src(e, is32, i, E);
        int d = edge_dst(e, is32, i, E);
        if ((unsigned)s < (unsigned)N && (unsigned)d < (unsigned)N) {
            int p = atomicAdd(&cur[d >> RB_LOG], 1);
            ebuf[p] = ((u64)(unsigned)d << 32) | (unsigned)s;
        }
    }
}

// ---------------- P4: per-bucket CSR finalize (all in LDS; RB=256, 391 blocks) ------------
__global__ __launch_bounds__(256) void p4_finalize_kernel(const u64* __restrict__ ebuf,
                                                          const int* __restrict__ bstart,
                                                          int* __restrict__ rowptr,
                                                          float* __restrict__ dinv,
                                                          int* __restrict__ col, int N) {
    __shared__ int cnt[RB];
    __shared__ int lrp[RB];
    __shared__ int wsums[4], wpre[4];
    const int b = blockIdx.x;
    const int t = threadIdx.x;
    const int e0 = bstart[b], e1 = bstart[b + 1];
    const int node0 = b << RB_LOG;
    int nn = N - node0; if (nn > RB) nn = RB;
    cnt[t] = 0;
    __syncthreads();
    for (int i = e0 + t; i < e1; i += 256) {
        int d = (int)(ebuf[i] >> 32);
        atomicAdd(&cnt[d - node0], 1);
    }
    __syncthreads();
    int v = cnt[t];
    const int lane = t & 63;
    int x = v;
#pragma unroll
    for (int off = 1; off < 64; off <<= 1) {
        int y = __shfl_up(x, off, 64);
        if (lane >= off) x += y;
    }
    if (lane == 63) wsums[t >> 6] = x;
    __syncthreads();
    if (t == 0) { int r = 0; for (int w = 0; w < 4; w++) { wpre[w] = r; r += wsums[w]; } }
    __syncthreads();
    int excl = wpre[t >> 6] + x - v;
    lrp[t] = excl;
    if (t < nn) {
        rowptr[node0 + t] = e0 + excl;
        dinv[node0 + t] = rsqrtf((float)(v + 1));
    }
    __syncthreads();
    for (int i = e0 + t; i < e1; i += 256) {
        u64 rec = ebuf[i];
        int d = (int)(rec >> 32);
        int p = atomicAdd(&lrp[d - node0], 1);
        col[e0 + p] = (int)(unsigned)rec;
    }
}

// ---------------- Weights bf16-transpose prep (merged W1 + W2) ----------------
__global__ void wbt2_kernel(const float* __restrict__ W1, unsigned short* __restrict__ w1bt,
                            const float* __restrict__ W2, unsigned short* __restrict__ w2bt) {
    int t = blockIdx.x * 256 + threadIdx.x;
    if (t < IN_F * HID1) {
        int c = t >> 8, k = t & 255;
        w1bt[t] = f2bf(W1[k * HID1 + c]);
    } else {
        int u = t - IN_F * HID1;
        if (u < HID1 * HID2) {
            int c = u >> 7, k = u & 127;
            w2bt[u] = f2bf(W2[k * HID2 + c]);
        }
    }
}

// ---------------- GEMM1 MFMA: h1b[N,128](bf16) = x[N,256] @ W1[256,128] ----------------
__global__ __launch_bounds__(256) void gemm1_mfma_kernel(const float* __restrict__ x,
                                                         const unsigned short* __restrict__ Wbt,
                                                         unsigned short* __restrict__ hb, int N) {
    __shared__ unsigned short As[64 * 64];
    __shared__ unsigned short Bs[128 * 64];
    const int t = threadIdx.x;
    const int w = t >> 6;
    const int l = t & 63;
    const int lrow = l & 15;
    const int g = l >> 4;
    const int row0 = blockIdx.x * 64;

    f32x4 acc[4][2];
#pragma unroll
    for (int m = 0; m < 4; m++)
#pragma unroll
        for (int n = 0; n < 2; n++) acc[m][n] = (f32x4){0.f, 0.f, 0.f, 0.f};

    for (int kc = 0; kc < 4; kc++) {
        __syncthreads();
#pragma unroll
        for (int it = 0; it < 2; it++) {
            int slot = it * 256 + t;
            int r = slot >> 3;
            int k0 = (slot & 7) * 8;
            int grow = row0 + r;
            float4 v0 = make_float4(0.f, 0.f, 0.f, 0.f), v1 = v0;
            if (grow < N) {
                const float* p = &x[(long long)grow * IN_F + kc * 64 + k0];
                v0 = *(const float4*)p;
                v1 = *(const float4*)(p + 4);
            }
            ushort8 u;
            u[0] = f2bf(v0.x); u[1] = f2bf(v0.y); u[2] = f2bf(v0.z); u[3] = f2bf(v0.w);
            u[4] = f2bf(v1.x); u[5] = f2bf(v1.y); u[6] = f2bf(v1.z); u[7] = f2bf(v1.w);
            *(ushort8*)&As[r * 64 + (k0 ^ ((r & 7) << 3))] = u;
        }
#pragma unroll
        for (int it = 0; it < 4; it++) {
            int slot = it * 256 + t;
            int c = slot >> 3;
            int k0 = (slot & 7) * 8;
            ushort8 u = *(const ushort8*)&Wbt[c * IN_F + kc * 64 + k0];
            *(ushort8*)&Bs[c * 64 + (k0 ^ ((c & 7) << 3))] = u;
        }
        __syncthreads();
#pragma unroll
        for (int ks = 0; ks < 2; ks++) {
            int kk = ks * 32 + g * 8;
            bf16x8 af[4], bfr[2];
#pragma unroll
            for (int m = 0; m < 4; m++) {
                int r = m * 16 + lrow;
                af[m] = *(bf16x8*)&As[r * 64 + (kk ^ ((r & 7) << 3))];
            }
#pragma unroll
            for (int n = 0; n < 2; n++) {
                int c = w * 32 + n * 16 + lrow;
                bfr[n] = *(bf16x8*)&Bs[c * 64 + (kk ^ ((c & 7) << 3))];
            }
#pragma unroll
            for (int m = 0; m < 4; m++)
#pragma unroll
                for (int n = 0; n < 2; n++)
                    acc[m][n] = __builtin_amdgcn_mfma_f32_16x16x32_bf16(af[m], bfr[n], acc[m][n], 0, 0, 0);
        }
    }
#pragma unroll
    for (int m = 0; m < 4; m++) {
        int rbase = row0 + m * 16 + g * 4;
#pragma unroll
        for (int j = 0; j < 4; j++) {
            int grow = rbase + j;
            if (grow < N) {
#pragma unroll
                for (int n = 0; n < 2; n++)
                    hb[(long long)grow * HID1 + w * 32 + n * 16 + lrow] = f2bf(acc[m][n][j]);
            }
        }
    }
}

// ---------------- GEMM2 MFMA: h2b[N,64](bf16) = agg1b[N,128](bf16) @ W2[128,64] -----------
__global__ __launch_bounds__(256) void gemm2_mfma_kernel(const unsigned short* __restrict__ ab,
                                                         const unsigned short* __restrict__ Wbt,
                                                         unsigned short* __restrict__ hb, int N) {
    __shared__ unsigned short As[64 * 64];
    __shared__ unsigned short Bs[64 * 64];
    const int t = threadIdx.x;
    const int w = t >> 6;
    const int l = t & 63;
    const int lrow = l & 15;
    const int g = l >> 4;
    const int row0 = blockIdx.x * 64;

    f32x4 acc[4];
#pragma unroll
    for (int m = 0; m < 4; m++) acc[m] = (f32x4){0.f, 0.f, 0.f, 0.f};

    for (int kc = 0; kc < 2; kc++) {
        __syncthreads();
#pragma unroll
        for (int it = 0; it < 2; it++) {
            int slot = it * 256 + t;
            int r = slot >> 3;
            int k0 = (slot & 7) * 8;
            int grow = row0 + r;
            ushort8 u = (ushort8){0, 0, 0, 0, 0, 0, 0, 0};
            if (grow < N)
                u = *(const ushort8*)&ab[(long long)grow * HID1 + kc * 64 + k0];
            *(ushort8*)&As[r * 64 + (k0 ^ ((r & 7) << 3))] = u;
        }
#pragma unroll
        for (int it = 0; it < 2; it++) {
            int slot = it * 256 + t;
            int c = slot >> 3;
            int k0 = (slot & 7) * 8;
            ushort8 u = *(const ushort8*)&Wbt[c * HID1 + kc * 64 + k0];
            *(ushort8*)&Bs[c * 64 + (k0 ^ ((c & 7) << 3))] = u;
        }
        __syncthreads();
#pragma unroll
        for (int ks = 0; ks < 2; ks++) {
            int kk = ks * 32 + g * 8;
            bf16x8 af[4], bfr;
#pragma unroll
            for (int m = 0; m < 4; m++) {
                int r = m * 16 + lrow;
                af[m] = *(bf16x8*)&As[r * 64 + (kk ^ ((r & 7) << 3))];
            }
            {
                int c = w * 16 + lrow;
                bfr = *(bf16x8*)&Bs[c * 64 + (kk ^ ((c & 7) << 3))];
            }
#pragma unroll
            for (int m = 0; m < 4; m++)
                acc[m] = __builtin_amdgcn_mfma_f32_16x16x32_bf16(af[m], bfr, acc[m], 0, 0, 0);
        }
    }
#pragma unroll
    for (int m = 0; m < 4; m++) {
        int rbase = row0 + m * 16 + g * 4;
#pragma unroll
        for (int j = 0; j < 4; j++) {
            int grow = rbase + j;
            if (grow < N)
                hb[(long long)grow * HID2 + w * 16 + lrow] = f2bf(acc[m][j]);
        }
    }
}

// ---------------- CSR gather (bf16 features, 8-wide named-var unroll, no wave cap) --------
template <int G, bool RELUBF>
__global__ __launch_bounds__(256) void gather_bf16_kernel(const unsigned short* __restrict__ hb,
                                                          const float* __restrict__ bias,
                                                          const float* __restrict__ dinv,
                                                          const int* __restrict__ rowptr,
                                                          const int* __restrict__ col,
                                                          void* __restrict__ out, int N) {
    long long tid = (long long)blockIdx.x * 256 + threadIdx.x;
    int node = (int)(tid / G);
    int g = (int)(tid % G);
    if (node >= N) return;
    const ushort8* h8 = (const ushort8*)hb;
    float di = dinv[node];
    ushort8 hv = h8[(long long)node * G + g];
    float sum[8];
#pragma unroll
    for (int j = 0; j < 8; j++) sum[j] = di * bf2f(hv[j]);
    int p0 = rowptr[node], p1 = rowptr[node + 1];
    int p = p0;
    for (; p + 7 < p1; p += 8) {
        int s0 = col[p], s1 = col[p + 1], s2 = col[p + 2], s3 = col[p + 3];
        int s4 = col[p + 4], s5 = col[p + 5], s6 = col[p + 6], s7 = col[p + 7];
        ushort8 v0 = h8[(long long)s0 * G + g];
        ushort8 v1 = h8[(long long)s1 * G + g];
        ushort8 v2 = h8[(long long)s2 * G + g];
        ushort8 v3 = h8[(long long)s3 * G + g];
        ushort8 v4 = h8[(long long)s4 * G + g];
        ushort8 v5 = h8[(long long)s5 * G + g];
        ushort8 v6 = h8[(long long)s6 * G + g];
        ushort8 v7 = h8[(long long)s7 * G + g];
        float w0 = dinv[s0], w1 = dinv[s1], w2 = dinv[s2], w3 = dinv[s3];
        float w4 = dinv[s4], w5 = dinv[s5], w6 = dinv[s6], w7 = dinv[s7];
#pragma unroll
        for (int j = 0; j < 8; j++)
            sum[j] += ((w0 * bf2f(v0[j]) + w1 * bf2f(v1[j])) +
                       (w2 * bf2f(v2[j]) + w3 * bf2f(v3[j]))) +
                      ((w4 * bf2f(v4[j]) + w5 * bf2f(v5[j])) +
                       (w6 * bf2f(v6[j]) + w7 * bf2f(v7[j])));
    }
    for (; p + 3 < p1; p += 4) {
        int s0 = col[p], s1 = col[p + 1], s2 = col[p + 2], s3 = col[p + 3];
        float w0 = dinv[s0], w1 = dinv[s1], w2 = dinv[s2], w3 = dinv[s3];
        ushort8 v0 = h8[(long long)s0 * G + g];
        ushort8 v1 = h8[(long long)s1 * G + g];
        ushort8 v2 = h8[(long long)s2 * G + g];
        ushort8 v3 = h8[(long long)s3 * G + g];
#pragma unroll
        for (int j = 0; j < 8; j++)
            sum[j] += (w0 * bf2f(v0[j]) + w1 * bf2f(v1[j])) +
                      (w2 * bf2f(v2[j]) + w3 * bf2f(v3[j]));
    }
    for (; p < p1; p++) {
        int s0 = col[p];
        float w0 = dinv[s0];
        ushort8 v0 = h8[(long long)s0 * G + g];
#pragma unroll
        for (int j = 0; j < 8; j++) sum[j] += w0 * bf2f(v0[j]);
    }
    float4 b0 = ((const float4*)bias)[g * 2];
    float4 b1 = ((const float4*)bias)[g * 2 + 1];
    float r[8];
    r[0] = b0.x + di * sum[0]; r[1] = b0.y + di * sum[1];
    r[2] = b0.z + di * sum[2]; r[3] = b0.w + di * sum[3];
    r[4] = b1.x + di * sum[4]; r[5] = b1.y + di * sum[5];
    r[6] = b1.z + di * sum[6]; r[7] = b1.w + di * sum[7];
    if (RELUBF) {
        ushort8 u;
#pragma unroll
        for (int j = 0; j < 8; j++) u[j] = f2bf(fmaxf(r[j], 0.f));
        ((ushort8*)out)[(long long)node * G + g] = u;
    } else {
        float4 o0 = make_float4(r[0], r[1], r[2], r[3]);
        float4 o1 = make_float4(r[4], r[5], r[6], r[7]);
        float4* op = (float4*)((float*)out + ((long long)node * G + g) * 8);
        op[0] = o0;
        op[1] = o1;
    }
}

extern "C" void kernel_launch(void* const* d_in, const int* in_sizes, int n_in,
                              void* d_out, int out_size, void* d_ws, size_t ws_size,
                              hipStream_t stream) {
    const float* x  = (const float*)d_in[0];
    const void*  ei = d_in[1];
    const float* W1 = (const float*)d_in[2];
    const float* b1 = (const float*)d_in[3];
    const float* W2 = (const float*)d_in[4];
    const float* b2 = (const float*)d_in[5];
    float* out = (float*)d_out;

    const int N = in_sizes[0] / IN_F;          // 100000
    const int E = in_sizes[1] / 2;             // 1600000
    const int nbk = (N + RB - 1) >> RB_LOG;    // 391 (must be <= 512)
    const int chunk = (E + NBLK - 1) / NBLK;   // 6250

    char* ws = (char*)d_ws;
    size_t off = 0;
    auto alloc = [&](size_t bytes) -> char* {
        char* p = ws + off;
        off = (off + bytes + 255) & ~(size_t)255;
        return p;
    };
    int*   flag   = (int*)alloc(4);
    int*   bhist  = (int*)alloc((size_t)512 * NBLK * 4);
    int*   tot    = (int*)alloc(512 * 4);
    int*   bstart = (int*)alloc(520 * 4);
    float* dinv   = (float*)alloc((size_t)N * 4);
    int*   rowptr = (int*)alloc((size_t)(N + 1) * 4);
    u64*   ebuf   = (u64*)alloc((size_t)E * 8);
    int*   col    = (int*)alloc((size_t)E * 4);
    unsigned short* w1bt  = (unsigned short*)alloc((size_t)HID1 * IN_F * 2);
    unsigned short* w2bt  = (unsigned short*)alloc((size_t)HID2 * HID1 * 2);
    unsigned short* h1b   = (unsigned short*)alloc((size_t)N * HID1 * 2);
    unsigned short* agg1b = (unsigned short*)alloc((size_t)N * HID1 * 2);
    unsigned short* h2b   = (unsigned short*)alloc((size_t)N * HID2 * 2);

    hipMemsetAsync(flag, 0, sizeof(int), stream);

    long long nOdd = E < 4096 ? (long long)E : 4096;
    detect_kernel<<<1, 256, 0, stream>>>((const int*)ei, nOdd, flag);

    // CSR build: bucket partition, zero global atomics
    p1_count_kernel<<<NBLK, 256, 0, stream>>>(ei, flag, bhist, N, E, nbk, chunk);
    p2a_kernel<<<nbk, 256, 0, stream>>>(bhist, tot);
    p2b_kernel<<<1, 512, 0, stream>>>(tot, bstart, rowptr, nbk, N);
    p3_scatter_kernel<<<NBLK, 256, 0, stream>>>(ei, flag, bhist, bstart, ebuf, N, E, nbk, chunk);
    p4_finalize_kernel<<<nbk, 256, 0, stream>>>(ebuf, bstart, rowptr, dinv, col, N);

    wbt2_kernel<<<(IN_F * HID1 + HID1 * HID2 + 255) / 256, 256, 0, stream>>>(W1, w1bt, W2, w2bt);

    // Layer 1: MFMA GEMM -> gather (relu+bf16 fused)
    gemm1_mfma_kernel<<<(N + 63) / 64, 256, 0, stream>>>(x, w1bt, h1b, N);
    gather_bf16_kernel<16, true><<<(int)(((long long)N * 16 + 255) / 256), 256, 0, stream>>>(
        h1b, b1, dinv, rowptr, col, agg1b, N);

    // Layer 2: MFMA GEMM (bf16 A) -> gather (f32 out)
    gemm2_mfma_kernel<<<(N + 63) / 64, 256, 0, stream>>>(agg1b, w2bt, h2b, N);
    gather_bf16_kernel<8, false><<<(int)(((long long)N * 8 + 255) / 256), 256, 0, stream>>>(
        h2b, b2, dinv, rowptr, col, out, N);
}

// Round 20
// 186.841 us; speedup vs baseline: 1.0328x; 1.0328x over previous
//
#include <hip/hip_runtime.h>

#define IN_F 256
#define HID1 128
#define HID2 64
#define NBLK 256      // edge-partition blocks
#define RB_LOG 8
#define RB 256        // nodes per bucket -> nbk = 391 for N=100000

typedef __bf16 bf16x8 __attribute__((ext_vector_type(8)));
typedef float f32x4 __attribute__((ext_vector_type(4)));
typedef unsigned short ushort8 __attribute__((ext_vector_type(8)));
typedef unsigned long long u64;

__device__ inline unsigned short f2bf(float f) {
    unsigned int u = __float_as_uint(f);
    u += 0x7fffu + ((u >> 16) & 1u);
    return (unsigned short)(u >> 16);
}
__device__ inline float bf2f(unsigned short u) {
    return __uint_as_float(((unsigned int)u) << 16);
}

// ---------------- index-format detection (sampled: first nOdd odd words) ----------------
__global__ void detect_kernel(const int* __restrict__ e, long long nOdd, int* flag) {
    long long stride = (long long)gridDim.x * blockDim.x;
    for (long long i = (long long)blockIdx.x * blockDim.x + threadIdx.x; i < nOdd; i += stride) {
        if (e[2 * i + 1] != 0) { *flag = 1; return; }
    }
}

__device__ inline int edge_src(const void* e, const int is32, long long i, int E) {
    return is32 ? ((const int*)e)[i] : (int)((const long long*)e)[i];
}
__device__ inline int edge_dst(const void* e, const int is32, long long i, int E) {
    return is32 ? ((const int*)e)[E + i] : (int)((const long long*)e)[E + i];
}

// ---------------- P1: per-block bucket histograms (LDS, no global atomics) ----------------
__global__ __launch_bounds__(256) void p1_count_kernel(const void* __restrict__ e,
                                                       const int* __restrict__ flag,
                                                       int* __restrict__ bhist,
                                                       int N, int E, int nbk, int chunk) {
    __shared__ int hist[512];
    const int is32 = *flag;
    const int blk = blockIdx.x;
    const int t = threadIdx.x;
    for (int j = t; j < nbk; j += 256) hist[j] = 0;
    __syncthreads();
    long long lo = (long long)blk * chunk;
    long long hi = lo + chunk; if (hi > E) hi = E;
    for (long long i = lo + t; i < hi; i += 256) {
        int s = edge_src(e, is32, i, E);
        int d = edge_dst(e, is32, i, E);
        if ((unsigned)s < (unsigned)N && (unsigned)d < (unsigned)N)
            atomicAdd(&hist[d >> RB_LOG], 1);
    }
    __syncthreads();
    for (int j = t; j < nbk; j += 256) bhist[j * NBLK + blk] = hist[j];   // bucket-major
}

// ---------------- P2a: exclusive scan of each bucket row (256 entries) ----------------
__global__ __launch_bounds__(256) void p2a_kernel(int* __restrict__ bhist, int* __restrict__ tot) {
    __shared__ int wsums[4], wpre[4];
    const int b = blockIdx.x;
    const int t = threadIdx.x;
    int v = bhist[b * NBLK + t];
    const int lane = t & 63;
    int x = v;
#pragma unroll
    for (int off = 1; off < 64; off <<= 1) {
        int y = __shfl_up(x, off, 64);
        if (lane >= off) x += y;
    }
    if (lane == 63) wsums[t >> 6] = x;
    __syncthreads();
    if (t == 0) { int r = 0; for (int w = 0; w < 4; w++) { wpre[w] = r; r += wsums[w]; } }
    __syncthreads();
    int excl = wpre[t >> 6] + x - v;
    bhist[b * NBLK + t] = excl;
    if (t == 255) tot[b] = excl + v;
}

// ---------------- P2b: scan bucket totals -> bstart (512-thread shfl scan) ----------------
__global__ __launch_bounds__(512) void p2b_kernel(const int* __restrict__ tot,
                                                  int* __restrict__ bstart,
                                                  int* __restrict__ rowptr, int nbk, int N) {
    __shared__ int wsums[8], wpre[8];
    const int t = threadIdx.x;
    int v = (t < nbk) ? tot[t] : 0;
    const int lane = t & 63;
    int x = v;
#pragma unroll
    for (int off = 1; off < 64; off <<= 1) {
        int y = __shfl_up(x, off, 64);
        if (lane >= off) x += y;
    }
    if (lane == 63) wsums[t >> 6] = x;
    __syncthreads();
    if (t == 0) { int r = 0; for (int w = 0; w < 8; w++) { wpre[w] = r; r += wsums[w]; } }
    __syncthreads();
    int excl = wpre[t >> 6] + x - v;
    if (t < nbk) bstart[t] = excl;
    if (t == 511) {
        int total = wpre[7] + wsums[7];
        bstart[nbk] = total;
        rowptr[N] = total;
    }
}

// ---------------- P3: scatter edges into bucket-major ebuf (LDS cursors) ----------------
__global__ __launch_bounds__(256) void p3_scatter_kernel(const void* __restrict__ e,
                                                         const int* __restrict__ flag,
                                                         const int* __restrict__ bhist,
                                                         const int* __restrict__ bstart,
                                                         u64* __restrict__ ebuf,
                                                         int N, int E, int nbk, int chunk) {
    __shared__ int cur[512];
    const int is32 = *flag;
    const int blk = blockIdx.x;
    const int t = threadIdx.x;
    for (int j = t; j < nbk; j += 256) cur[j] = bhist[j * NBLK + blk] + bstart[j];
    __syncthreads();
    long long lo = (long long)blk * chunk;
    long long hi = lo + chunk; if (hi > E) hi = E;
    for (long long i = lo + t; i < hi; i += 256) {
        int s = edge_src(e, is32, i, E);
        int d = edge_dst(e, is32, i, E);
        if ((unsigned)s < (unsigned)N && (unsigned)d < (unsigned)N) {
            int p = atomicAdd(&cur[d >> RB_LOG], 1);
            ebuf[p] = ((u64)(unsigned)d << 32) | (unsigned)s;
        }
    }
}

// ---------------- P4: per-bucket CSR finalize (all in LDS; RB=256, 391 blocks) ------------
__global__ __launch_bounds__(256) void p4_finalize_kernel(const u64* __restrict__ ebuf,
                                                          const int* __restrict__ bstart,
                                                          int* __restrict__ rowptr,
                                                          float* __restrict__ dinv,
                                                          int* __restrict__ col, int N) {
    __shared__ int cnt[RB];
    __shared__ int lrp[RB];
    __shared__ int wsums[4], wpre[4];
    const int b = blockIdx.x;
    const int t = threadIdx.x;
    const int e0 = bstart[b], e1 = bstart[b + 1];
    const int node0 = b << RB_LOG;
    int nn = N - node0; if (nn > RB) nn = RB;
    cnt[t] = 0;
    __syncthreads();
    for (int i = e0 + t; i < e1; i += 256) {
        int d = (int)(ebuf[i] >> 32);
        atomicAdd(&cnt[d - node0], 1);
    }
    __syncthreads();
    int v = cnt[t];
    const int lane = t & 63;
    int x = v;
#pragma unroll
    for (int off = 1; off < 64; off <<= 1) {
        int y = __shfl_up(x, off, 64);
        if (lane >= off) x += y;
    }
    if (lane == 63) wsums[t >> 6] = x;
    __syncthreads();
    if (t == 0) { int r = 0; for (int w = 0; w < 4; w++) { wpre[w] = r; r += wsums[w]; } }
    __syncthreads();
    int excl = wpre[t >> 6] + x - v;
    lrp[t] = excl;
    if (t < nn) {
        rowptr[node0 + t] = e0 + excl;
        dinv[node0 + t] = rsqrtf((float)(v + 1));
    }
    __syncthreads();
    for (int i = e0 + t; i < e1; i += 256) {
        u64 rec = ebuf[i];
        int d = (int)(rec >> 32);
        int p = atomicAdd(&lrp[d - node0], 1);
        col[e0 + p] = (int)(unsigned)rec;
    }
}

// ---------------- Weights bf16-transpose prep (merged W1 + W2) ----------------
__global__ void wbt2_kernel(const float* __restrict__ W1, unsigned short* __restrict__ w1bt,
                            const float* __restrict__ W2, unsigned short* __restrict__ w2bt) {
    int t = blockIdx.x * 256 + threadIdx.x;
    if (t < IN_F * HID1) {
        int c = t >> 8, k = t & 255;
        w1bt[t] = f2bf(W1[k * HID1 + c]);
    } else {
        int u = t - IN_F * HID1;
        if (u < HID1 * HID2) {
            int c = u >> 7, k = u & 127;
            w2bt[u] = f2bf(W2[k * HID2 + c]);
        }
    }
}

// ---------------- GEMM1 MFMA: h1b[N,128](bf16) = x[N,256] @ W1[256,128] ----------------
__global__ __launch_bounds__(256) void gemm1_mfma_kernel(const float* __restrict__ x,
                                                         const unsigned short* __restrict__ Wbt,
                                                         unsigned short* __restrict__ hb, int N) {
    __shared__ unsigned short As[64 * 64];
    __shared__ unsigned short Bs[128 * 64];
    const int t = threadIdx.x;
    const int w = t >> 6;
    const int l = t & 63;
    const int lrow = l & 15;
    const int g = l >> 4;
    const int row0 = blockIdx.x * 64;

    f32x4 acc[4][2];
#pragma unroll
    for (int m = 0; m < 4; m++)
#pragma unroll
        for (int n = 0; n < 2; n++) acc[m][n] = (f32x4){0.f, 0.f, 0.f, 0.f};

    for (int kc = 0; kc < 4; kc++) {
        __syncthreads();
#pragma unroll
        for (int it = 0; it < 2; it++) {
            int slot = it * 256 + t;
            int r = slot >> 3;
            int k0 = (slot & 7) * 8;
            int grow = row0 + r;
            float4 v0 = make_float4(0.f, 0.f, 0.f, 0.f), v1 = v0;
            if (grow < N) {
                const float* p = &x[(long long)grow * IN_F + kc * 64 + k0];
                v0 = *(const float4*)p;
                v1 = *(const float4*)(p + 4);
            }
            ushort8 u;
            u[0] = f2bf(v0.x); u[1] = f2bf(v0.y); u[2] = f2bf(v0.z); u[3] = f2bf(v0.w);
            u[4] = f2bf(v1.x); u[5] = f2bf(v1.y); u[6] = f2bf(v1.z); u[7] = f2bf(v1.w);
            *(ushort8*)&As[r * 64 + (k0 ^ ((r & 7) << 3))] = u;
        }
#pragma unroll
        for (int it = 0; it < 4; it++) {
            int slot = it * 256 + t;
            int c = slot >> 3;
            int k0 = (slot & 7) * 8;
            ushort8 u = *(const ushort8*)&Wbt[c * IN_F + kc * 64 + k0];
            *(ushort8*)&Bs[c * 64 + (k0 ^ ((c & 7) << 3))] = u;
        }
        __syncthreads();
#pragma unroll
        for (int ks = 0; ks < 2; ks++) {
            int kk = ks * 32 + g * 8;
            bf16x8 af[4], bfr[2];
#pragma unroll
            for (int m = 0; m < 4; m++) {
                int r = m * 16 + lrow;
                af[m] = *(bf16x8*)&As[r * 64 + (kk ^ ((r & 7) << 3))];
            }
#pragma unroll
            for (int n = 0; n < 2; n++) {
                int c = w * 32 + n * 16 + lrow;
                bfr[n] = *(bf16x8*)&Bs[c * 64 + (kk ^ ((c & 7) << 3))];
            }
#pragma unroll
            for (int m = 0; m < 4; m++)
#pragma unroll
                for (int n = 0; n < 2; n++)
                    acc[m][n] = __builtin_amdgcn_mfma_f32_16x16x32_bf16(af[m], bfr[n], acc[m][n], 0, 0, 0);
        }
    }
#pragma unroll
    for (int m = 0; m < 4; m++) {
        int rbase = row0 + m * 16 + g * 4;
#pragma unroll
        for (int j = 0; j < 4; j++) {
            int grow = rbase + j;
            if (grow < N) {
#pragma unroll
                for (int n = 0; n < 2; n++)
                    hb[(long long)grow * HID1 + w * 32 + n * 16 + lrow] = f2bf(acc[m][n][j]);
            }
        }
    }
}

// ---------------- GEMM2 MFMA: h2b[N,64](bf16) = agg1b[N,128](bf16) @ W2[128,64] -----------
__global__ __launch_bounds__(256) void gemm2_mfma_kernel(const unsigned short* __restrict__ ab,
                                                         const unsigned short* __restrict__ Wbt,
                                                         unsigned short* __restrict__ hb, int N) {
    __shared__ unsigned short As[64 * 64];
    __shared__ unsigned short Bs[64 * 64];
    const int t = threadIdx.x;
    const int w = t >> 6;
    const int l = t & 63;
    const int lrow = l & 15;
    const int g = l >> 4;
    const int row0 = blockIdx.x * 64;

    f32x4 acc[4];
#pragma unroll
    for (int m = 0; m < 4; m++) acc[m] = (f32x4){0.f, 0.f, 0.f, 0.f};

    for (int kc = 0; kc < 2; kc++) {
        __syncthreads();
#pragma unroll
        for (int it = 0; it < 2; it++) {
            int slot = it * 256 + t;
            int r = slot >> 3;
            int k0 = (slot & 7) * 8;
            int grow = row0 + r;
            ushort8 u = (ushort8){0, 0, 0, 0, 0, 0, 0, 0};
            if (grow < N)
                u = *(const ushort8*)&ab[(long long)grow * HID1 + kc * 64 + k0];
            *(ushort8*)&As[r * 64 + (k0 ^ ((r & 7) << 3))] = u;
        }
#pragma unroll
        for (int it = 0; it < 2; it++) {
            int slot = it * 256 + t;
            int c = slot >> 3;
            int k0 = (slot & 7) * 8;
            ushort8 u = *(const ushort8*)&Wbt[c * HID1 + kc * 64 + k0];
            *(ushort8*)&Bs[c * 64 + (k0 ^ ((c & 7) << 3))] = u;
        }
        __syncthreads();
#pragma unroll
        for (int ks = 0; ks < 2; ks++) {
            int kk = ks * 32 + g * 8;
            bf16x8 af[4], bfr;
#pragma unroll
            for (int m = 0; m < 4; m++) {
                int r = m * 16 + lrow;
                af[m] = *(bf16x8*)&As[r * 64 + (kk ^ ((r & 7) << 3))];
            }
            {
                int c = w * 16 + lrow;
                bfr = *(bf16x8*)&Bs[c * 64 + (kk ^ ((c & 7) << 3))];
            }
#pragma unroll
            for (int m = 0; m < 4; m++)
                acc[m] = __builtin_amdgcn_mfma_f32_16x16x32_bf16(af[m], bfr, acc[m], 0, 0, 0);
        }
    }
#pragma unroll
    for (int m = 0; m < 4; m++) {
        int rbase = row0 + m * 16 + g * 4;
#pragma unroll
        for (int j = 0; j < 4; j++) {
            int grow = rbase + j;
            if (grow < N)
                hb[(long long)grow * HID2 + w * 16 + lrow] = f2bf(acc[m][j]);
        }
    }
}

// ---------------- CSR gather (bf16 features, 4-wide unroll — proven-best form) ------------
template <int G, bool RELUBF>
__global__ __launch_bounds__(256) void gather_bf16_kernel(const unsigned short* __restrict__ hb,
                                                          const float* __restrict__ bias,
                                                          const float* __restrict__ dinv,
                                                          const int* __restrict__ rowptr,
                                                          const int* __restrict__ col,
                                                          void* __restrict__ out, int N) {
    long long tid = (long long)blockIdx.x * 256 + threadIdx.x;
    int node = (int)(tid / G);
    int g = (int)(tid % G);
    if (node >= N) return;
    const ushort8* h8 = (const ushort8*)hb;
    float di = dinv[node];
    ushort8 hv = h8[(long long)node * G + g];
    float sum[8];
#pragma unroll
    for (int j = 0; j < 8; j++) sum[j] = di * bf2f(hv[j]);
    int p0 = rowptr[node], p1 = rowptr[node + 1];
    int p = p0;
    for (; p + 3 < p1; p += 4) {
        int s0 = col[p], s1 = col[p + 1], s2 = col[p + 2], s3 = col[p + 3];
        float w0 = dinv[s0], w1 = dinv[s1], w2 = dinv[s2], w3 = dinv[s3];
        ushort8 v0 = h8[(long long)s0 * G + g];
        ushort8 v1 = h8[(long long)s1 * G + g];
        ushort8 v2 = h8[(long long)s2 * G + g];
        ushort8 v3 = h8[(long long)s3 * G + g];
#pragma unroll
        for (int j = 0; j < 8; j++)
            sum[j] += (w0 * bf2f(v0[j]) + w1 * bf2f(v1[j])) +
                      (w2 * bf2f(v2[j]) + w3 * bf2f(v3[j]));
    }
    for (; p < p1; p++) {
        int s0 = col[p];
        float w0 = dinv[s0];
        ushort8 v0 = h8[(long long)s0 * G + g];
#pragma unroll
        for (int j = 0; j < 8; j++) sum[j] += w0 * bf2f(v0[j]);
    }
    float4 b0 = ((const float4*)bias)[g * 2];
    float4 b1 = ((const float4*)bias)[g * 2 + 1];
    float r[8];
    r[0] = b0.x + di * sum[0]; r[1] = b0.y + di * sum[1];
    r[2] = b0.z + di * sum[2]; r[3] = b0.w + di * sum[3];
    r[4] = b1.x + di * sum[4]; r[5] = b1.y + di * sum[5];
    r[6] = b1.z + di * sum[6]; r[7] = b1.w + di * sum[7];
    if (RELUBF) {
        ushort8 u;
#pragma unroll
        for (int j = 0; j < 8; j++) u[j] = f2bf(fmaxf(r[j], 0.f));
        ((ushort8*)out)[(long long)node * G + g] = u;
    } else {
        float4 o0 = make_float4(r[0], r[1], r[2], r[3]);
        float4 o1 = make_float4(r[4], r[5], r[6], r[7]);
        float4* op = (float4*)((float*)out + ((long long)node * G + g) * 8);
        op[0] = o0;
        op[1] = o1;
    }
}

extern "C" void kernel_launch(void* const* d_in, const int* in_sizes, int n_in,
                              void* d_out, int out_size, void* d_ws, size_t ws_size,
                              hipStream_t stream) {
    const float* x  = (const float*)d_in[0];
    const void*  ei = d_in[1];
    const float* W1 = (const float*)d_in[2];
    const float* b1 = (const float*)d_in[3];
    const float* W2 = (const float*)d_in[4];
    const float* b2 = (const float*)d_in[5];
    float* out = (float*)d_out;

    const int N = in_sizes[0] / IN_F;          // 100000
    const int E = in_sizes[1] / 2;             // 1600000
    const int nbk = (N + RB - 1) >> RB_LOG;    // 391 (must be <= 512)
    const int chunk = (E + NBLK - 1) / NBLK;   // 6250

    char* ws = (char*)d_ws;
    size_t off = 0;
    auto alloc = [&](size_t bytes) -> char* {
        char* p = ws + off;
        off = (off + bytes + 255) & ~(size_t)255;
        return p;
    };
    int*   flag   = (int*)alloc(4);
    int*   bhist  = (int*)alloc((size_t)512 * NBLK * 4);
    int*   tot    = (int*)alloc(512 * 4);
    int*   bstart = (int*)alloc(520 * 4);
    float* dinv   = (float*)alloc((size_t)N * 4);
    int*   rowptr = (int*)alloc((size_t)(N + 1) * 4);
    u64*   ebuf   = (u64*)alloc((size_t)E * 8);
    int*   col    = (int*)alloc((size_t)E * 4);
    unsigned short* w1bt  = (unsigned short*)alloc((size_t)HID1 * IN_F * 2);
    unsigned short* w2bt  = (unsigned short*)alloc((size_t)HID2 * HID1 * 2);
    unsigned short* h1b   = (unsigned short*)alloc((size_t)N * HID1 * 2);
    unsigned short* agg1b = (unsigned short*)alloc((size_t)N * HID1 * 2);
    unsigned short* h2b   = (unsigned short*)alloc((size_t)N * HID2 * 2);

    hipMemsetAsync(flag, 0, sizeof(int), stream);

    long long nOdd = E < 4096 ? (long long)E : 4096;
    detect_kernel<<<1, 256, 0, stream>>>((const int*)ei, nOdd, flag);

    // CSR build: bucket partition, zero global atomics
    p1_count_kernel<<<NBLK, 256, 0, stream>>>(ei, flag, bhist, N, E, nbk, chunk);
    p2a_kernel<<<nbk, 256, 0, stream>>>(bhist, tot);
    p2b_kernel<<<1, 512, 0, stream>>>(tot, bstart, rowptr, nbk, N);
    p3_scatter_kernel<<<NBLK, 256, 0, stream>>>(ei, flag, bhist, bstart, ebuf, N, E, nbk, chunk);
    p4_finalize_kernel<<<nbk, 256, 0, stream>>>(ebuf, bstart, rowptr, dinv, col, N);

    wbt2_kernel<<<(IN_F * HID1 + HID1 * HID2 + 255) / 256, 256, 0, stream>>>(W1, w1bt, W2, w2bt);

    // Layer 1: MFMA GEMM -> gather (relu+bf16 fused)
    gemm1_mfma_kernel<<<(N + 63) / 64, 256, 0, stream>>>(x, w1bt, h1b, N);
    gather_bf16_kernel<16, true><<<(int)(((long long)N * 16 + 255) / 256), 256, 0, stream>>>(
        h1b, b1, dinv, rowptr, col, agg1b, N);

    // Layer 2: MFMA GEMM (bf16 A) -> gather (f32 out)
    gemm2_mfma_kernel<<<(N + 63) / 64, 256, 0, stream>>>(agg1b, w2bt, h2b, N);
    gather_bf16_kernel<8, false><<<(int)(((long long)N * 8 + 255) / 256), 256, 0, stream>>>(
        h2b, b2, dinv, rowptr, col, out, N);
}